// Round 2
// baseline (277.285 us; speedup 1.0000x reference)
//
#include <hip/hip_runtime.h>

// loss = -sum_i  dot(s_i, im_i) / ((||s_i||+EPS) * (||im_i||+EPS))
// s, im: fp32 [N=65536, D=512].  Latency-tolerant restructure:
//   8 threads per row, interleaved float4 ownership (coalesced per instr),
//   32 unrolled private loads per thread, shfl reduction only at the end.

#define EPSV 1.1e-13f   // 1e-13 + 1e-14, matches reference

__global__ void zero_out_kernel(float* out) {
    out[0] = 0.0f;
}

__global__ __launch_bounds__(256) void cosdiag_kernel(
        const float4* __restrict__ s,
        const float4* __restrict__ im,
        float* __restrict__ out,
        int nrows) {
    const int tid   = threadIdx.x;
    const int lane  = tid & 63;
    const int wave  = tid >> 6;
    const int gwave = blockIdx.x * 4 + wave;     // 4 waves/block
    const int oct   = lane & 7;                  // which 1/8 of the row
    const int lrow  = lane >> 3;                 // row within wave's 8-row group
    const int row   = gwave * 8 + lrow;

    float ss = 0.0f, ii = 0.0f, dt = 0.0f;

    if (row < nrows) {
        // float4 index: row*128 + j*8 + oct.  At fixed j, the wave's 64 lanes
        // cover 8 contiguous 128B runs (8 rows x 8 adjacent float4) = 16 fully
        // used 64B lines -> coalesced per instruction.
        const float4* __restrict__ srow = s  + (size_t)row * 128 + oct;
        const float4* __restrict__ irow = im + (size_t)row * 128 + oct;

        #pragma unroll
        for (int j = 0; j < 16; ++j) {
            float4 a = srow[(size_t)j * 8];
            float4 b = irow[(size_t)j * 8];
            ss += a.x*a.x + a.y*a.y + a.z*a.z + a.w*a.w;
            ii += b.x*b.x + b.y*b.y + b.z*b.z + b.w*b.w;
            dt += a.x*b.x + a.y*b.y + a.z*b.z + a.w*b.w;
        }
    }

    // Reduce across the 8 lanes sharing a row (xor 1,2,4) — 9 shfls per 8 rows.
    #pragma unroll
    for (int off = 1; off <= 4; off <<= 1) {
        ss += __shfl_xor(ss, off);
        ii += __shfl_xor(ii, off);
        dt += __shfl_xor(dt, off);
    }

    // Lane with oct==0 holds the full row sums; form the row's cosine.
    float contrib = (oct == 0 && row < nrows)
                  ? dt / ((sqrtf(ss) + EPSV) * (sqrtf(ii) + EPSV))
                  : 0.0f;

    // Sum the 8 row results within the wave (xor 8,16,32).
    #pragma unroll
    for (int off = 8; off <= 32; off <<= 1) {
        contrib += __shfl_xor(contrib, off);
    }

    __shared__ float part[4];
    if (lane == 0) part[wave] = contrib;
    __syncthreads();
    if (tid == 0) {
        atomicAdd(out, -(part[0] + part[1] + part[2] + part[3]));
    }
}

extern "C" void kernel_launch(void* const* d_in, const int* in_sizes, int n_in,
                              void* d_out, int out_size, void* d_ws, size_t ws_size,
                              hipStream_t stream) {
    const float* s  = (const float*)d_in[0];
    const float* im = (const float*)d_in[1];
    // d_in[2] = temp (unused by the loss)
    float* out = (float*)d_out;

    const int D = 512;
    const int nrows = in_sizes[0] / D;   // 65536

    // d_out is re-poisoned to 0xAA before every timed launch: zero it first.
    zero_out_kernel<<<1, 1, 0, stream>>>(out);

    // 8 threads/row, 256 threads/block -> 32 rows/block.
    const int rows_per_block = 32;
    int grid = (nrows + rows_per_block - 1) / rows_per_block;   // 2048

    cosdiag_kernel<<<grid, 256, 0, stream>>>(
        (const float4*)s, (const float4*)im, out, nrows);
}